// Round 13
// baseline (139.288 us; speedup 1.0000x reference)
//
#include <hip/hip_runtime.h>

#define NUM_HEADS 16
#define HEAD_DIM  128
#define SEQ       2048
#define KT_STRIDE 8192   // bf16 elems per k-tile group in KF/VF (16 chunks * 512)

typedef __attribute__((ext_vector_type(8))) unsigned short us8;
typedef __attribute__((ext_vector_type(8))) __bf16 bf16x8;
typedef __attribute__((ext_vector_type(4))) float f32x4;
typedef __attribute__((ext_vector_type(16))) float f32x16;
typedef __attribute__((ext_vector_type(4))) unsigned u32x4;

static __device__ inline unsigned short f2bf(float x) {   // RNE
    union { float f; unsigned u; } v; v.f = x;
    unsigned r = v.u + 0x7FFFu + ((v.u >> 16) & 1u);
    return (unsigned short)(r >> 16);
}
static __device__ inline unsigned pk2bf(float a, float b) {
    return (unsigned)f2bf(a) | ((unsigned)f2bf(b) << 16);
}
static __device__ inline float fast_exp2(float x) {
#if __has_builtin(__builtin_amdgcn_exp2f)
    return __builtin_amdgcn_exp2f(x);
#else
    return exp2f(x);
#endif
}
// pack hi16(clo) into lo half, hi16(chi) into hi half (both truncated bf16)
static __device__ inline unsigned pack_hi(unsigned clo, unsigned chi) {
#if __has_builtin(__builtin_amdgcn_perm)
    return __builtin_amdgcn_perm(chi, clo, 0x07060302u);
#else
    return (clo >> 16) | (chi & 0xffff0000u);
#endif
}
static __device__ inline f32x16 mfma32(us8 a, us8 b, f32x16 c) {
    return __builtin_amdgcn_mfma_f32_32x32x16_bf16(
        __builtin_bit_cast(bf16x8, a), __builtin_bit_cast(bf16x8, b), c, 0, 0, 0);
}

// ---------- pre-pass: write K and V^T in exact 32x32x16 A-fragment order ----------
__global__ __launch_bounds__(256)
void prep_frag(const float* __restrict__ K, const float* __restrict__ V,
               unsigned short* __restrict__ KF, unsigned short* __restrict__ VF)
{
    const int bx  = (int)blockIdx.x, t = (int)threadIdx.x;
    const int which = bx & 1, kt = (bx >> 1) & 31, kvh = bx >> 6;
    __shared__ __align__(16) float Ls[64][132];

    const float* src = (which ? V : K) + ((size_t)kvh * SEQ + kt * 64) * HEAD_DIM;
    #pragma unroll
    for (int i = 0; i < 8; ++i) {
        const int idx = t + i * 256;
        const int r = idx >> 5, c4 = idx & 31;
        *(float4*)&Ls[r][c4 * 4] = *(const float4*)(src + (size_t)r * HEAD_DIM + c4 * 4);
    }
    __syncthreads();

    if (!which) {  // K fragments
        #pragma unroll
        for (int i = 0; i < 4; ++i) {
            const int c = t + i * 256;              // 0..1023
            const int lane = c & 63, ds = (c >> 6) & 3, mat = (c >> 8) & 1, kh = c >> 9;
            const int H = lane >> 5;
            const int row = kh * 32 + (lane & 31);
            const int dim = mat * 64 + ds * 16 + H * 8;
            u32x4 pk;
            #pragma unroll
            for (int jj = 0; jj < 4; ++jj)
                pk[jj] = pk2bf(Ls[row][dim + 2*jj], Ls[row][dim + 2*jj + 1]);
            *(us8*)(KF + ((size_t)(kvh * 32 + kt) * 16 + kh * 8 + mat * 4 + ds) * 512 + lane * 8)
                = __builtin_bit_cast(us8, pk);
        }
    } else {       // V^T fragments
        #pragma unroll
        for (int i = 0; i < 4; ++i) {
            const int c = t + i * 256;
            const int lane = c & 63, db = (c >> 6) & 3, ks = (c >> 8) & 1, kh = c >> 9;
            const int H = lane >> 5;
            const int s0 = kh * 32 + ks * 16 + H * 8;
            const int d  = db * 32 + (lane & 31);
            u32x4 pk;
            #pragma unroll
            for (int jj = 0; jj < 4; ++jj)
                pk[jj] = pk2bf(Ls[s0 + 2*jj][d], Ls[s0 + 2*jj + 1][d]);
            *(us8*)(VF + ((size_t)(kvh * 32 + kt) * 16 + kh * 8 + ks * 4 + db) * 512 + lane * 8)
                = __builtin_bit_cast(us8, pk);
        }
    }
}

// ---------- main: streaming, register-P, 3 waves/SIMD, one q-tile per block ----------
__global__ __launch_bounds__(256, 3)
void diff_attn_mfma11(const float* __restrict__ Q,
                      const unsigned short* __restrict__ KF,
                      const unsigned short* __restrict__ VF,
                      float* __restrict__ Out)
{
    __shared__ float cb[2][32][136];   // epilogue-only combine buffer
    __shared__ float rsb[2][2][32];

    const int t   = (int)threadIdx.x;
    const int wv  = t >> 6;
    const int ln  = t & 63;
    const int mat = wv >> 1;        // 0: softmax1 (dims 0..63), 1: softmax2 (64..127)
    const int kh  = wv & 1;         // k-half of the 64-k tile
    const int q   = ln & 31;        // q-col
    const int H   = ln >> 5;

    // grid 1024 = 16 h x 64 q-tiles; longest-first so the tail is short blocks
    const int bx   = (int)blockIdx.x;
    const int h    = bx & 15;
    const int qt   = 63 - (bx >> 4);          // 63..0
    const int nkt  = (qt >> 1) + 1;           // 1..32
    const int q0   = qt * 32;
    const int kvh  = h >> 2;

    const unsigned short* kfb = KF + ((size_t)kvh * 32 * 16 + kh * 8 + mat * 4) * 512 + ln * 8;
    const unsigned short* vfb = VF + ((size_t)kvh * 32 * 16 + kh * 8) * 512 + ln * 8;

    const float qscale = 0.125f * 1.44269504088896340736f;  // 1/8 * log2(e)

    // ---- Q fragments (hi only; K already bf16 — error ~2.9e-3 vs 9.9e-3 threshold) ----
    us8 qhi[4];
    {
        const float* qr = Q + ((size_t)h * SEQ + q0 + q) * HEAD_DIM + mat * 64;
        #pragma unroll
        for (int ds = 0; ds < 4; ++ds) {
            const int d0 = ds * 16 + H * 8;
            float x[8];
            *(float4*)&x[0] = *(const float4*)(qr + d0);
            *(float4*)&x[4] = *(const float4*)(qr + d0 + 4);
            us8 hi8;
            #pragma unroll
            for (int j = 0; j < 8; ++j) hi8[j] = f2bf(x[j] * qscale);
            qhi[ds] = hi8;
        }
    }

    f32x16 o[4];                   // O^T: dim = db*32+(r&3)+8*(r>>2)+4H, q-col = q
    f32x4  rsv = (f32x4)0.f;       // row-sum partials
    #pragma unroll
    for (int i = 0; i < 4; ++i) o[i] = (f32x16)0.f;

    // body(j): kaIn holds K(j); kaOut <- K(j+1). Scores NOT pipelined across iters
    // (3rd wave/SIMD provides the latency cover instead of the s-dbuf).
    auto body = [&](int j, us8 (&kaIn)[4], us8 (&kaOut)[4]) {
        // V frags, ks=0 group (consumed after scores+exp: ~300 cyc of cover)
        us8 va0[4];
        {
            const unsigned short* vb = vfb + (size_t)j * KT_STRIDE;
            #pragma unroll
            for (int c = 0; c < 4; ++c) va0[c] = *(const us8*)(vb + c * 512);
        }
        // K prefetch for next iter
        if (j + 1 < nkt) {
            const unsigned short* kb = kfb + (size_t)(j + 1) * KT_STRIDE;
            #pragma unroll
            for (int ds = 0; ds < 4; ++ds) kaOut[ds] = *(const us8*)(kb + ds * 512);
        }
        // ---- scores for THIS k-tile ----
        f32x16 s = (f32x16)0.f;
        #pragma unroll
        for (int ds = 0; ds < 4; ++ds) s = mfma32(kaIn[ds], qhi[ds], s);
        // ---- exp2 (+ causal mask on diagonal tile only) ----
        unsigned c[16];
        if (j == nkt - 1) {
            const int kg0 = j * 64 + kh * 32 + 4 * H;
            const int qg  = q0 + q;
            #pragma unroll
            for (int r = 0; r < 16; ++r) {
                const int kg = kg0 + (r & 3) + ((r >> 2) << 3);
                float e = (kg <= qg) ? fast_exp2(s[r]) : 0.f;
                c[r] = __builtin_bit_cast(unsigned, e);
            }
        } else {
            #pragma unroll
            for (int r = 0; r < 16; ++r)
                c[r] = __builtin_bit_cast(unsigned, fast_exp2(s[r]));
        }
        // ---- ks=0: pack, row-sum, V ks=1 loads, C->B swap, PV ----
        us8 va1[4];
        #pragma unroll
        for (int ks = 0; ks < 2; ++ks) {
            const unsigned pA = pack_hi(c[8*ks+0], c[8*ks+1]);
            const unsigned pB = pack_hi(c[8*ks+2], c[8*ks+3]);
            const unsigned pC = pack_hi(c[8*ks+4], c[8*ks+5]);
            const unsigned pD = pack_hi(c[8*ks+6], c[8*ks+7]);
            rsv[0] += __builtin_bit_cast(float, pA << 16);
            rsv[1] += __builtin_bit_cast(float, pA & 0xffff0000u);
            rsv[2] += __builtin_bit_cast(float, pB << 16);
            rsv[3] += __builtin_bit_cast(float, pB & 0xffff0000u);
            rsv[0] += __builtin_bit_cast(float, pC << 16);
            rsv[1] += __builtin_bit_cast(float, pC & 0xffff0000u);
            rsv[2] += __builtin_bit_cast(float, pD << 16);
            rsv[3] += __builtin_bit_cast(float, pD & 0xffff0000u);
            if (ks == 0) {       // V ks=1 loads issued under ks=0's shuffle+PV
                const unsigned short* vb = vfb + (size_t)j * KT_STRIDE + 4 * 512;
                #pragma unroll
                for (int c2 = 0; c2 < 4; ++c2) va1[c2] = *(const us8*)(vb + c2 * 512);
            }
            const unsigned x1 = H ? pA : pC;
            const unsigned x2 = H ? pB : pD;
            const unsigned t1 = (unsigned)__shfl_xor((int)x1, 32, 64);
            const unsigned t2 = (unsigned)__shfl_xor((int)x2, 32, 64);
            u32x4 bw;
            bw[0] = H ? t1 : pA;
            bw[1] = H ? t2 : pB;
            bw[2] = H ? pC : t1;
            bw[3] = H ? pD : t2;
            const us8 bp = __builtin_bit_cast(us8, bw);
            #pragma unroll
            for (int db = 0; db < 4; ++db)
                o[db] = mfma32(ks ? va1[db] : va0[db], bp, o[db]);
        }
    };

    us8 kaA[4], kaB[4];
    #pragma unroll
    for (int ds = 0; ds < 4; ++ds) kaA[ds] = *(const us8*)(kfb + ds * 512);
    int j = 0;
    for (; j + 2 <= nkt; j += 2) {
        body(j,     kaA, kaB);
        body(j + 1, kaB, kaA);
    }
    if (j < nkt) body(j, kaA, kaB);

    // ---- epilogue: combine kh halves and mats through LDS ----
    __syncthreads();
    float rsc = (rsv[0] + rsv[1]) + (rsv[2] + rsv[3]);
    rsc += __shfl_xor(rsc, 32, 64);
    if (ln < 32) rsb[mat][kh][ln] = rsc;
    if (kh == 1) {
        #pragma unroll
        for (int db = 0; db < 4; ++db)
            #pragma unroll
            for (int i = 0; i < 4; ++i) {
                float4 v = { o[db][i*4+0], o[db][i*4+1], o[db][i*4+2], o[db][i*4+3] };
                *(float4*)&cb[mat][q][db * 32 + 8 * i + 4 * H] = v;
            }
    }
    __syncthreads();
    if (kh == 0) {
        const float l = rsb[mat][0][q] + rsb[mat][1][q];
        const float a = mat ? (0.16f / l) : (0.2f / l);
        #pragma unroll
        for (int db = 0; db < 4; ++db)
            #pragma unroll
            for (int i = 0; i < 4; ++i) {
                float4 v = *(float4*)&cb[mat][q][db * 32 + 8 * i + 4 * H];
                o[db][i*4+0] = (o[db][i*4+0] + v.x) * a;
                o[db][i*4+1] = (o[db][i*4+1] + v.y) * a;
                o[db][i*4+2] = (o[db][i*4+2] + v.z) * a;
                o[db][i*4+3] = (o[db][i*4+3] + v.w) * a;
            }
        if (mat == 1) {
            #pragma unroll
            for (int db = 0; db < 4; ++db)
                #pragma unroll
                for (int i = 0; i < 4; ++i) {
                    float4 v = { o[db][i*4+0], o[db][i*4+1], o[db][i*4+2], o[db][i*4+3] };
                    *(float4*)&cb[1][q][db * 32 + 8 * i + 4 * H] = v;
                }
        }
    }
    __syncthreads();
    if (wv == 0) {
        float* ob = Out + ((size_t)h * SEQ + q0 + q) * HEAD_DIM;
        #pragma unroll
        for (int db = 0; db < 4; ++db)
            #pragma unroll
            for (int i = 0; i < 4; ++i) {
                float4 v = *(float4*)&cb[1][q][db * 32 + 8 * i + 4 * H];
                float4 r;
                r.x = o[db][i*4+0] - v.x;
                r.y = o[db][i*4+1] - v.y;
                r.z = o[db][i*4+2] - v.z;
                r.w = o[db][i*4+3] - v.w;
                *(float4*)(ob + db * 32 + 8 * i + 4 * H) = r;
            }
    }
}

extern "C" void kernel_launch(void* const* d_in, const int* in_sizes, int n_in,
                              void* d_out, int out_size, void* d_ws, size_t ws_size,
                              hipStream_t stream) {
    const float* Q = (const float*)d_in[0];
    const float* K = (const float*)d_in[1];
    const float* V = (const float*)d_in[2];
    float* Out = (float*)d_out;

    unsigned short* KF = (unsigned short*)d_ws;             // 2 MB
    unsigned short* VF = KF + (size_t)4 * SEQ * HEAD_DIM;   // 2 MB

    prep_frag<<<256, 256, 0, stream>>>(K, V, KF, VF);
    diff_attn_mfma11<<<1024, 256, 0, stream>>>(Q, KF, VF, Out);
}

// Round 14
// 114.085 us; speedup vs baseline: 1.2209x; 1.2209x over previous
//
#include <hip/hip_runtime.h>

#define NUM_HEADS 16
#define HEAD_DIM  128
#define SEQ       2048
#define KT_STRIDE 8192   // bf16 elems per k-tile group in KF/VF (16 chunks * 512)
#define VBYTES    16384  // one V tile in LDS

typedef __attribute__((ext_vector_type(8))) unsigned short us8;
typedef __attribute__((ext_vector_type(8))) __bf16 bf16x8;
typedef __attribute__((ext_vector_type(4))) float f32x4;
typedef __attribute__((ext_vector_type(16))) float f32x16;
typedef __attribute__((ext_vector_type(4))) unsigned u32x4;

static __device__ inline unsigned short f2bf(float x) {   // RNE
    union { float f; unsigned u; } v; v.f = x;
    unsigned r = v.u + 0x7FFFu + ((v.u >> 16) & 1u);
    return (unsigned short)(r >> 16);
}
static __device__ inline unsigned pk2bf(float a, float b) {
    return (unsigned)f2bf(a) | ((unsigned)f2bf(b) << 16);
}
static __device__ inline float fast_exp2(float x) {
#if __has_builtin(__builtin_amdgcn_exp2f)
    return __builtin_amdgcn_exp2f(x);
#else
    return exp2f(x);
#endif
}
// pack hi16(clo) into lo half, hi16(chi) into hi half (both truncated bf16)
static __device__ inline unsigned pack_hi(unsigned clo, unsigned chi) {
#if __has_builtin(__builtin_amdgcn_perm)
    return __builtin_amdgcn_perm(chi, clo, 0x07060302u);
#else
    return (clo >> 16) | (chi & 0xffff0000u);
#endif
}
static __device__ inline f32x16 mfma32(us8 a, us8 b, f32x16 c) {
    return __builtin_amdgcn_mfma_f32_32x32x16_bf16(
        __builtin_bit_cast(bf16x8, a), __builtin_bit_cast(bf16x8, b), c, 0, 0, 0);
}

// ---------- pre-pass: write K and V^T in exact 32x32x16 A-fragment order ----------
__global__ __launch_bounds__(256)
void prep_frag(const float* __restrict__ K, const float* __restrict__ V,
               unsigned short* __restrict__ KF, unsigned short* __restrict__ VF)
{
    const int bx  = (int)blockIdx.x, t = (int)threadIdx.x;
    const int which = bx & 1, kt = (bx >> 1) & 31, kvh = bx >> 6;
    __shared__ __align__(16) float Ls[64][132];

    const float* src = (which ? V : K) + ((size_t)kvh * SEQ + kt * 64) * HEAD_DIM;
    #pragma unroll
    for (int i = 0; i < 8; ++i) {
        const int idx = t + i * 256;
        const int r = idx >> 5, c4 = idx & 31;
        *(float4*)&Ls[r][c4 * 4] = *(const float4*)(src + (size_t)r * HEAD_DIM + c4 * 4);
    }
    __syncthreads();

    if (!which) {  // K fragments
        #pragma unroll
        for (int i = 0; i < 4; ++i) {
            const int c = t + i * 256;              // 0..1023
            const int lane = c & 63, ds = (c >> 6) & 3, mat = (c >> 8) & 1, kh = c >> 9;
            const int H = lane >> 5;
            const int row = kh * 32 + (lane & 31);
            const int dim = mat * 64 + ds * 16 + H * 8;
            u32x4 pk;
            #pragma unroll
            for (int jj = 0; jj < 4; ++jj)
                pk[jj] = pk2bf(Ls[row][dim + 2*jj], Ls[row][dim + 2*jj + 1]);
            *(us8*)(KF + ((size_t)(kvh * 32 + kt) * 16 + kh * 8 + mat * 4 + ds) * 512 + lane * 8)
                = __builtin_bit_cast(us8, pk);
        }
    } else {       // V^T fragments
        #pragma unroll
        for (int i = 0; i < 4; ++i) {
            const int c = t + i * 256;
            const int lane = c & 63, db = (c >> 6) & 3, ks = (c >> 8) & 1, kh = c >> 9;
            const int H = lane >> 5;
            const int s0 = kh * 32 + ks * 16 + H * 8;
            const int d  = db * 32 + (lane & 31);
            u32x4 pk;
            #pragma unroll
            for (int jj = 0; jj < 4; ++jj)
                pk[jj] = pk2bf(Ls[s0 + 2*jj][d], Ls[s0 + 2*jj + 1][d]);
            *(us8*)(VF + ((size_t)(kvh * 32 + kt) * 16 + kh * 8 + ks * 4 + db) * 512 + lane * 8)
                = __builtin_bit_cast(us8, pk);
        }
    }
}

// ---------- main: K register-streamed, V via LDS dbuf (L2 traffic 48->32 KB/iter) ----------
__global__ __launch_bounds__(256, 2)
void diff_attn_mfma12(const float* __restrict__ Q,
                      const unsigned short* __restrict__ KF,
                      const unsigned short* __restrict__ VF,
                      float* __restrict__ Out)
{
    __shared__ __align__(16) unsigned char vbuf[2][VBYTES];   // V tile dbuf (32 KB)
    __shared__ float cb[2][32][136];                          // epilogue combine buffer
    __shared__ float rsb[2][2][32];

    const int t   = (int)threadIdx.x;
    const int wv  = t >> 6;
    const int ln  = t & 63;
    const int mat = wv >> 1;        // 0: softmax1 (dims 0..63), 1: softmax2 (64..127)
    const int kh  = wv & 1;         // k-half of the 64-k tile
    const int q   = ln & 31;        // q-col
    const int H   = ln >> 5;

    // grid 512 = 16 h x 32 pair-slots; block does q-tiles (idx, 63-idx) sequentially
    const int bx   = (int)blockIdx.x;
    const int h    = bx & 15;
    const int idx  = bx >> 4;                 // 0..31
    const int qtA  = idx, qtB = 63 - idx;
    const int nktA = (qtA >> 1) + 1;          // nktA + nktB = 33
    const int kvh  = h >> 2;

    const unsigned short* kfb = KF + ((size_t)kvh * 32 * 16 + kh * 8 + mat * 4) * 512 + ln * 8;
    const unsigned short* vfbase = VF + (size_t)kvh * 32 * KT_STRIDE;

    const float qscale = 0.125f * 1.44269504088896340736f;  // 1/8 * log2(e)

    us8 qhi[4];
    auto loadQ = [&](int q0c) {
        const float* qr = Q + ((size_t)h * SEQ + q0c + q) * HEAD_DIM + mat * 64;
        #pragma unroll
        for (int ds = 0; ds < 4; ++ds) {
            const int d0 = ds * 16 + H * 8;
            float x[8];
            *(float4*)&x[0] = *(const float4*)(qr + d0);
            *(float4*)&x[4] = *(const float4*)(qr + d0 + 4);
            us8 hi8;
            #pragma unroll
            for (int j = 0; j < 8; ++j) hi8[j] = f2bf(x[j] * qscale);
            qhi[ds] = hi8;
        }
    };

    // async whole-tile V stage: 16 KB = 4 passes x 256 lanes x 16 B (wave-uniform LDS base)
    auto issueV = [&](int j, int p) {
        const unsigned short* src = vfbase + (size_t)j * KT_STRIDE;
        #pragma unroll
        for (int i = 0; i < 4; ++i) {
            const int off = i * 256 + wv * 64;      // chunk-of-16B index, lane adds ln*16
            __builtin_amdgcn_global_load_lds(
                (const __attribute__((address_space(1))) unsigned*)(src + (size_t)(off + ln) * 8),
                (__attribute__((address_space(3))) unsigned*)(&vbuf[p][(size_t)off * 16]),
                16, 0, 0);
        }
    };

    f32x16 o[4];                   // O^T: dim = db*32+(r&3)+8*(r>>2)+4H, q-col = q
    f32x4  rsv;                    // row-sum partials

    auto epilogue = [&](int q0c) {
        __syncthreads();
        float rsc = (rsv[0] + rsv[1]) + (rsv[2] + rsv[3]);
        rsc += __shfl_xor(rsc, 32, 64);
        if (ln < 32) rsb[mat][kh][ln] = rsc;
        if (kh == 1) {
            #pragma unroll
            for (int db = 0; db < 4; ++db)
                #pragma unroll
                for (int i = 0; i < 4; ++i) {
                    float4 v = { o[db][i*4+0], o[db][i*4+1], o[db][i*4+2], o[db][i*4+3] };
                    *(float4*)&cb[mat][q][db * 32 + 8 * i + 4 * H] = v;
                }
        }
        __syncthreads();
        if (kh == 0) {
            const float l = rsb[mat][0][q] + rsb[mat][1][q];
            const float a = mat ? (0.16f / l) : (0.2f / l);
            #pragma unroll
            for (int db = 0; db < 4; ++db)
                #pragma unroll
                for (int i = 0; i < 4; ++i) {
                    float4 v = *(float4*)&cb[mat][q][db * 32 + 8 * i + 4 * H];
                    o[db][i*4+0] = (o[db][i*4+0] + v.x) * a;
                    o[db][i*4+1] = (o[db][i*4+1] + v.y) * a;
                    o[db][i*4+2] = (o[db][i*4+2] + v.z) * a;
                    o[db][i*4+3] = (o[db][i*4+3] + v.w) * a;
                }
            if (mat == 1) {
                #pragma unroll
                for (int db = 0; db < 4; ++db)
                    #pragma unroll
                    for (int i = 0; i < 4; ++i) {
                        float4 v = { o[db][i*4+0], o[db][i*4+1], o[db][i*4+2], o[db][i*4+3] };
                        *(float4*)&cb[1][q][db * 32 + 8 * i + 4 * H] = v;
                    }
            }
        }
        __syncthreads();
        if (wv == 0) {
            float* ob = Out + ((size_t)h * SEQ + q0c + q) * HEAD_DIM;
            #pragma unroll
            for (int db = 0; db < 4; ++db)
                #pragma unroll
                for (int i = 0; i < 4; ++i) {
                    float4 v = *(float4*)&cb[1][q][db * 32 + 8 * i + 4 * H];
                    float4 r;
                    r.x = o[db][i*4+0] - v.x;
                    r.y = o[db][i*4+1] - v.y;
                    r.z = o[db][i*4+2] - v.z;
                    r.w = o[db][i*4+3] - v.w;
                    *(float4*)(ob + db * 32 + 8 * i + 4 * H) = r;
                }
        }
        __syncthreads();   // cb reads done before next segment touches LDS
    };

    // one causal segment; scores pipelined one tile ahead; V via LDS dbuf with
    // top-of-iter barrier (prefetch issued AFTER barrier -> full-iter cover)
    auto run_seg = [&](int q0c, int nseg) {
        us8 kaA[4], kaB[4];

        auto body = [&](int j, int cur, us8 (&kaIn)[4], us8 (&kaOut)[4],
                        f32x16& sIn, f32x16& sOut) {
            __syncthreads();                        // vbuf[cur] ready; prev reads done
            if (j + 1 < nseg) issueV(j + 1, cur ^ 1);
            if (j + 2 < nseg) {
                const unsigned short* kb = kfb + (size_t)(j + 2) * KT_STRIDE;
                #pragma unroll
                for (int ds = 0; ds < 4; ++ds) kaOut[ds] = *(const us8*)(kb + ds * 512);
            }
            // scores for next k-tile (independent MFMA work covering this iter's VALU)
            sOut = (f32x16)0.f;
            if (j + 1 < nseg) {
                #pragma unroll
                for (int ds = 0; ds < 4; ++ds) sOut = mfma32(kaIn[ds], qhi[ds], sOut);
            }
            // V frags from LDS (issued early; consumed after exp2+pack ~150 cyc later)
            us8 va[8];
            #pragma unroll
            for (int c2 = 0; c2 < 8; ++c2)
                va[c2] = *(const us8*)(&vbuf[cur][(size_t)((kh * 8 + c2) * 64 + ln) * 16]);
            // exp2 (+ causal mask on diagonal tile only)
            unsigned c[16];
            if (j == nseg - 1) {
                const int kg0 = j * 64 + kh * 32 + 4 * H;
                const int qg  = q0c + q;
                #pragma unroll
                for (int r = 0; r < 16; ++r) {
                    const int kg = kg0 + (r & 3) + ((r >> 2) << 3);
                    float e = (kg <= qg) ? fast_exp2(sIn[r]) : 0.f;
                    c[r] = __builtin_bit_cast(unsigned, e);
                }
            } else {
                #pragma unroll
                for (int r = 0; r < 16; ++r)
                    c[r] = __builtin_bit_cast(unsigned, fast_exp2(sIn[r]));
            }
            // pack to bf16 (truncation), denominator from QUANTIZED P, C->B swap, PV
            #pragma unroll
            for (int ks = 0; ks < 2; ++ks) {
                const unsigned pA = pack_hi(c[8*ks+0], c[8*ks+1]);
                const unsigned pB = pack_hi(c[8*ks+2], c[8*ks+3]);
                const unsigned pC = pack_hi(c[8*ks+4], c[8*ks+5]);
                const unsigned pD = pack_hi(c[8*ks+6], c[8*ks+7]);
                rsv[0] += __builtin_bit_cast(float, pA << 16);
                rsv[1] += __builtin_bit_cast(float, pA & 0xffff0000u);
                rsv[2] += __builtin_bit_cast(float, pB << 16);
                rsv[3] += __builtin_bit_cast(float, pB & 0xffff0000u);
                rsv[0] += __builtin_bit_cast(float, pC << 16);
                rsv[1] += __builtin_bit_cast(float, pC & 0xffff0000u);
                rsv[2] += __builtin_bit_cast(float, pD << 16);
                rsv[3] += __builtin_bit_cast(float, pD & 0xffff0000u);
                const unsigned x1 = H ? pA : pC;
                const unsigned x2 = H ? pB : pD;
                const unsigned t1 = (unsigned)__shfl_xor((int)x1, 32, 64);
                const unsigned t2 = (unsigned)__shfl_xor((int)x2, 32, 64);
                u32x4 bw;
                bw[0] = H ? t1 : pA;
                bw[1] = H ? t2 : pB;
                bw[2] = H ? pC : t1;
                bw[3] = H ? pD : t2;
                const us8 bp = __builtin_bit_cast(us8, bw);
                #pragma unroll
                for (int db = 0; db < 4; ++db)
                    o[db] = mfma32(va[ks * 4 + db], bp, o[db]);
            }
        };

        // prologue: V(0) async into buf0; K(0) -> scores; K(1) into kaA
        issueV(0, 0);
        f32x16 s0, s1;
        #pragma unroll
        for (int ds = 0; ds < 4; ++ds) kaA[ds] = *(const us8*)(kfb + ds * 512);
        s0 = (f32x16)0.f;
        #pragma unroll
        for (int ds = 0; ds < 4; ++ds) s0 = mfma32(kaA[ds], qhi[ds], s0);
        if (nseg > 1) {
            #pragma unroll
            for (int ds = 0; ds < 4; ++ds) kaA[ds] = *(const us8*)(kfb + KT_STRIDE + ds * 512);
        }

        int j = 0;
        for (; j + 2 <= nseg; j += 2) {
            body(j,     0, kaA, kaB, s0, s1);
            body(j + 1, 1, kaB, kaA, s1, s0);
        }
        if (j < nseg) body(j, j & 1, kaA, kaB, s0, s1);
    };

    // ---- q-tile A then q-tile B (33 main iterations total, every block) ----
    loadQ(qtA * 32);
    #pragma unroll
    for (int i = 0; i < 4; ++i) o[i] = (f32x16)0.f;
    rsv = (f32x4)0.f;
    run_seg(qtA * 32, nktA);
    epilogue(qtA * 32);

    loadQ(qtB * 32);
    #pragma unroll
    for (int i = 0; i < 4; ++i) o[i] = (f32x16)0.f;
    rsv = (f32x4)0.f;
    run_seg(qtB * 32, 33 - nktA);
    epilogue(qtB * 32);
}

extern "C" void kernel_launch(void* const* d_in, const int* in_sizes, int n_in,
                              void* d_out, int out_size, void* d_ws, size_t ws_size,
                              hipStream_t stream) {
    const float* Q = (const float*)d_in[0];
    const float* K = (const float*)d_in[1];
    const float* V = (const float*)d_in[2];
    float* Out = (float*)d_out;

    unsigned short* KF = (unsigned short*)d_ws;             // 2 MB
    unsigned short* VF = KF + (size_t)4 * SEQ * HEAD_DIM;   // 2 MB

    prep_frag<<<256, 256, 0, stream>>>(K, V, KF, VF);
    diff_attn_mfma12<<<512, 256, 0, stream>>>(Q, KF, VF, Out);
}